// Round 7
// baseline (235.962 us; speedup 1.0000x reference)
//
#include <hip/hip_runtime.h>
#include <hip/hip_fp16.h>

#define BLANKC 59
#define NEGF (-1e30f)

typedef _Float16 half8 __attribute__((ext_vector_type(8)));

// ---------------- Phase 1: log-softmax + gather, TRANSPOSED output ----------
// em layout: [B][48 slots][T] halves. slot l (0..44) = logp[lab[b][l]],
// slot 45 = logp[BLANK]. One block per (b, 64-t tile); 4 lanes cooperate per t.
#define TTILE 64
__global__ __launch_bounds__(256)
void ctc_emit(const int* __restrict__ labels, const float* __restrict__ logits,
              __half* __restrict__ em, int T, int V, int L) {
    const int tiles_per_b = 384 / TTILE;                 // T = 384
    const int b  = blockIdx.x / tiles_per_b;
    const int t0 = (blockIdx.x % tiles_per_b) * TTILE;
    const int tid = threadIdx.x;

    __shared__ float ftile[TTILE][61];                   // stride 61: conflict-free
    __shared__ __half otile[48][72];                     // stride 72 halves (16B rows)

    // --- load 64 rows x 60 logits, coalesced dwords ---
    const float* src = logits + ((long)b * T + t0) * V;  // 3840 contiguous floats
    #pragma unroll
    for (int it = 0; it < 15; ++it) {
        const int idx = it * 256 + tid;                  // 0..3839
        const int r = idx / 60, c = idx - r * 60;
        ftile[r][c] = src[idx];
    }
    __syncthreads();

    // --- LSE + gather: 4 lanes per t (15 exps each, quad-combine) ---
    {
        const int t = tid >> 2;                          // 0..63
        const int q = tid & 3;                           // quarter of vocab
        float s = 0.f;
        #pragma unroll
        for (int k = 0; k < 15; ++k) s += __expf(ftile[t][q * 15 + k]);
        s += __shfl_xor(s, 1, 64);
        s += __shfl_xor(s, 2, 64);
        const float lse = __logf(s);
        const int* lab = labels + (long)b * L;
        #pragma unroll
        for (int j = 0; j < 12; ++j) {
            const int l = q * 12 + j;                    // q=3 covers 36..45
            if (l < 46) {
                const int v = (l < 45) ? lab[l] : BLANKC;
                otile[l][t] = __float2half(ftile[t][v] - lse);
            }
        }
    }
    __syncthreads();

    // --- cooperative transposed store: 46 slots x 64 halves (128 B each) ---
    for (int i = tid; i < 46 * 8; i += 256) {
        const int slot = i >> 3, seg = i & 7;
        const float4 v = *(const float4*)&otile[slot][seg * 8];
        float4* dst = (float4*)(em + ((long)b * 48 + slot) * T + t0 + seg * 8);
        *dst = v;
    }
}

// ---------------- Phase 2: alpha recurrence, one wave per batch element -----
// Lane l owns s0 = 2l (blank) and s1 = 2l+1 (label l). One shfl_up per step.
// asm pins force chunk values into VGPRs (compiler otherwise sinks the loads
// onto the serial chain -- proven R5/R6: VGPR_Count stayed 12/16).
__global__ __launch_bounds__(64)
void ctc_alpha(const int* __restrict__ labels, const __half* __restrict__ em,
               float* __restrict__ out, int T, int L, float inv_b) {
    const int b    = blockIdx.x;
    const int lane = threadIdx.x;

    const int* lab = labels + (long)b * L;
    const int labL = (lane < L) ? lab[lane] : BLANKC;
    const int labP = (lane >= 1 && lane < L) ? lab[lane - 1] : BLANKC;
    const bool skip = (lane >= 1) && (lane < L) && (labL != BLANKC) && (labL != labP);

    unsigned long long mk = __ballot((lane < L) && (labL != BLANKC));
    const int len = __popcll(mk);

    const int li = (lane < 46) ? lane : 45;
    const half8* rowL = (const half8*)(em + ((long)b * 48 + li) * T);
    const half8* rowB = (const half8*)(em + ((long)b * 48 + 45) * T);

    half8 curL = rowL[0], curB = rowB[0];
    half8 n1L  = rowL[1], n1B  = rowB[1];
    half8 n2L  = rowL[2], n2B  = rowB[2];
    asm volatile("" : "+v"(curL), "+v"(curB));       // force-resident before use

    float a0 = (lane == 0) ? (float)curB[0] : NEGF;  // s=0: blank @ t=0
    float a1 = (lane == 0) ? (float)curL[0] : NEGF;  // s=1: first label @ t=0
    float m01 = fmaxf(a0, a1);                       // hoisted off next step's chain

    auto step = [&](float eL, float eB) {
        float p = __shfl_up(a1, 1, 64);              // alpha_old[2l-1]
        p = (lane >= 1) ? p : NEGF;
        const float ps = skip ? p : NEGF;
        const float m0 = fmaxf(a0, p);
        const float na0 = m0 + __logf(__expf(a0 - m0) + __expf(p - m0)) + eB;
        const float m1 = fmaxf(m01, ps);
        const float na1 = m1 + __logf(__expf(a1 - m1) + __expf(a0 - m1) + __expf(ps - m1)) + eL;
        a0 = na0; a1 = na1;
        m01 = fmaxf(a0, a1);
    };

    // peeled chunk 0: t = 1..7
    #pragma unroll
    for (int i = 1; i < 8; ++i) step((float)curL[i], (float)curB[i]);

    const int NC = T / 8;                            // 48 chunks
    for (int c = 1; c < NC; ++c) {
        curL = n1L; curB = n1B;
        n1L = n2L;  n1B = n2B;
        if (c + 2 < NC) { n2L = rowL[c + 2]; n2B = rowB[c + 2]; }
        // pin: forces curL/curB (loaded 2 iters ago) into regs HERE, and keeps
        // the n1/n2 rotation as real register copies rather than re-loads.
        asm volatile("" : "+v"(curL), "+v"(curB), "+v"(n1L), "+v"(n1B));
        #pragma unroll
        for (int i = 0; i < 8; ++i) step((float)curL[i], (float)curB[i]);
    }

    // epilogue: end = 2*len -> lane len's a0; end-1 -> lane (len-1)'s a1
    const float ab2 = __shfl(a0, len, 64);
    float al2 = __shfl(a1, (len > 0) ? len - 1 : 0, 64);
    al2 = (len > 0) ? al2 : NEGF;
    if (lane == 0) {
        const float mm  = fmaxf(ab2, al2);
        const float nll = -(mm + __logf(__expf(ab2 - mm) + __expf(al2 - mm)));
        atomicAdd(out, nll * inv_b);
    }
}

extern "C" void kernel_launch(void* const* d_in, const int* in_sizes, int n_in,
                              void* d_out, int out_size, void* d_ws, size_t ws_size,
                              hipStream_t stream) {
    const int* labels   = (const int*)d_in[0];
    const float* logits = (const float*)d_in[1];
    float* out          = (float*)d_out;
    __half* em          = (__half*)d_ws;        // B*48*T*2 = 36 MB

    const int L = 45, V = 60;
    const int B = in_sizes[0] / L;
    const int T = in_sizes[1] / (B * V);

    hipMemsetAsync(out, 0, (size_t)out_size * sizeof(float), stream);
    ctc_emit<<<B * (T / TTILE), 256, 0, stream>>>(labels, logits, em, T, V, L);
    ctc_alpha<<<B, 64, 0, stream>>>(labels, em, out, T, L, 1.0f / (float)B);
}

// Round 8
// 213.706 us; speedup vs baseline: 1.1041x; 1.1041x over previous
//
#include <hip/hip_runtime.h>
#include <hip/hip_fp16.h>

#define BLANKC 59
#define NEGF (-1e30f)

typedef _Float16 half8 __attribute__((ext_vector_type(8)));

// Wave-wide shift-right-by-1 via DPP: VALU-speed cross-lane (vs ds_bpermute
// ~120 cy at 1 wave/SIMD). Lane 0 receives `fill` (old value, bound_ctrl=0).
__device__ __forceinline__ float wave_shr1(float x, float fill) {
    int r = __builtin_amdgcn_update_dpp(__float_as_int(fill), __float_as_int(x),
                                        0x138 /* WAVE_SHR:1 */, 0xF, 0xF, false);
    return __int_as_float(r);
}

// ---------------- Phase 1: log-softmax + gather, TRANSPOSED output ----------
// em layout: [B][48 slots][T] halves. slot l (0..44) = logp[lab[b][l]],
// slot 45 = logp[BLANK]. One block per (b, 64-t tile); 4 lanes cooperate per t.
#define TTILE 64
__global__ __launch_bounds__(256)
void ctc_emit(const int* __restrict__ labels, const float* __restrict__ logits,
              __half* __restrict__ em, int T, int V, int L) {
    const int tiles_per_b = 384 / TTILE;                 // T = 384
    const int b  = blockIdx.x / tiles_per_b;
    const int t0 = (blockIdx.x % tiles_per_b) * TTILE;
    const int tid = threadIdx.x;

    __shared__ float ftile[TTILE][61];                   // stride 61: conflict-free
    __shared__ __half otile[48][72];                     // stride 72 halves (16B rows)

    const float* src = logits + ((long)b * T + t0) * V;  // 3840 contiguous floats
    #pragma unroll
    for (int it = 0; it < 15; ++it) {
        const int idx = it * 256 + tid;                  // 0..3839
        const int r = idx / 60, c = idx - r * 60;
        ftile[r][c] = src[idx];
    }
    __syncthreads();

    {   // LSE + gather: 4 lanes per t
        const int t = tid >> 2;
        const int q = tid & 3;
        float s = 0.f;
        #pragma unroll
        for (int k = 0; k < 15; ++k) s += __expf(ftile[t][q * 15 + k]);
        s += __shfl_xor(s, 1, 64);
        s += __shfl_xor(s, 2, 64);
        const float lse = __logf(s);
        const int* lab = labels + (long)b * L;
        #pragma unroll
        for (int j = 0; j < 12; ++j) {
            const int l = q * 12 + j;
            if (l < 46) {
                const int v = (l < 45) ? lab[l] : BLANKC;
                otile[l][t] = __float2half(ftile[t][v] - lse);
            }
        }
    }
    __syncthreads();

    for (int i = tid; i < 46 * 8; i += 256) {
        const int slot = i >> 3, seg = i & 7;
        const float4 v = *(const float4*)&otile[slot][seg * 8];
        float4* dst = (float4*)(em + ((long)b * 48 + slot) * T + t0 + seg * 8);
        *dst = v;
    }
}

// ---------------- Phase 2: alpha recurrence, one wave per batch element -----
// Lane l owns s0 = 2l (blank) and s1 = 2l+1 (label l). Emissions staged in
// LDS so a compiler-sunk load costs <=1 lgkmcnt wait per 8 steps, and the
// cross-lane op is DPP (VALU) instead of ds_bpermute.
#define RS 400   // LDS row stride in halves: 16B-aligned rows, mild b128 conflict
__global__ __launch_bounds__(64)
void ctc_alpha(const int* __restrict__ labels, const __half* __restrict__ em,
               float* __restrict__ out, int T, int L, float inv_b) {
    const int b    = blockIdx.x;
    const int lane = threadIdx.x;

    __shared__ __half S[46 * RS];                        // 36.8 KB -> 4 blocks/CU

    // cooperative copy: em[b] slots 0..45 (T halves each) -> LDS rows
    const __half* emb = em + (long)b * 48 * T;
    const int NSEG = T / 8;                              // 48
    for (int i = lane; i < 46 * NSEG; i += 64) {
        const int r = i / NSEG, seg = i - r * NSEG;
        const half8 v = *(const half8*)(emb + r * T + seg * 8);
        *(half8*)(&S[r * RS + seg * 8]) = v;
    }
    __syncthreads();

    const int* lab = labels + (long)b * L;
    const int labL = (lane < L) ? lab[lane] : BLANKC;
    const int labP = (lane >= 1 && lane < L) ? lab[lane - 1] : BLANKC;
    const bool skip = (lane >= 1) && (lane < L) && (labL != BLANKC) && (labL != labP);

    unsigned long long mk = __ballot((lane < L) && (labL != BLANKC));
    const int len = __popcll(mk);

    const int li = (lane < 46) ? lane : 45;
    const __half* rowL = &S[li * RS];                    // this lane's slot row
    const __half* rowB = &S[45 * RS];                    // blank row (uniform)

    half8 curL = *(const half8*)(rowL);
    half8 curB = *(const half8*)(rowB);

    float a0 = (lane == 0) ? (float)curB[0] : NEGF;      // s=0: blank @ t=0
    float a1 = (lane == 0) ? (float)curL[0] : NEGF;      // s=1: first label @ t=0
    float m01 = fmaxf(a0, a1);                           // off-chain hoist

    auto step = [&](float eL, float eB) {
        const float p  = wave_shr1(a1, NEGF);            // alpha_old[2l-1]
        const float ps = skip ? p : NEGF;
        const float m0 = fmaxf(a0, p);
        const float na0 = m0 + __logf(__expf(a0 - m0) + __expf(p - m0)) + eB;
        const float m1 = fmaxf(m01, ps);
        const float na1 = m1 + __logf(__expf(a1 - m1) + __expf(a0 - m1) + __expf(ps - m1)) + eL;
        a0 = na0; a1 = na1;
        m01 = fmaxf(na0, na1);
    };

    // chunk 0: t = 1..7
    #pragma unroll
    for (int i = 1; i < 8; ++i) step((float)curL[i], (float)curB[i]);

    for (int c = 1; c < NSEG; ++c) {
        const half8 nL = *(const half8*)(rowL + c * 8);
        const half8 nB = *(const half8*)(rowB + c * 8);
        #pragma unroll
        for (int i = 0; i < 8; ++i) step((float)nL[i], (float)nB[i]);
    }

    // epilogue: end = 2*len -> lane len's a0; end-1 -> lane (len-1)'s a1
    const float ab2 = __shfl(a0, len, 64);
    float al2 = __shfl(a1, (len > 0) ? len - 1 : 0, 64);
    al2 = (len > 0) ? al2 : NEGF;
    if (lane == 0) {
        const float mm  = fmaxf(ab2, al2);
        const float nll = -(mm + __logf(__expf(ab2 - mm) + __expf(al2 - mm)));
        atomicAdd(out, nll * inv_b);
    }
}

extern "C" void kernel_launch(void* const* d_in, const int* in_sizes, int n_in,
                              void* d_out, int out_size, void* d_ws, size_t ws_size,
                              hipStream_t stream) {
    const int* labels   = (const int*)d_in[0];
    const float* logits = (const float*)d_in[1];
    float* out          = (float*)d_out;
    __half* em          = (__half*)d_ws;        // B*48*T*2 = 36 MB

    const int L = 45, V = 60;
    const int B = in_sizes[0] / L;
    const int T = in_sizes[1] / (B * V);

    hipMemsetAsync(out, 0, (size_t)out_size * sizeof(float), stream);
    ctc_emit<<<B * (T / TTILE), 256, 0, stream>>>(labels, logits, em, T, V, L);
    ctc_alpha<<<B, 64, 0, stream>>>(labels, em, out, T, L, 1.0f / (float)B);
}